// Round 1
// baseline (31.602 us; speedup 1.0000x reference)
//
#include <hip/hip_runtime.h>

// S4D Vandermonde kernel: K[h,l] = 2*Re( sum_n Ceff[h,n] * exp(dtA[h,n]*l) )
// Ceff = C * (exp(dtA)-1)/A,  dtA = dt*(-exp(log_A_real) + i*A_imag)
//
// Strategy: per (h,n), exp(dtA*l) is geometric in l -> complex-multiply
// recurrence instead of per-element transcendentals. Thread t of a block
// owns l = l0 + t + s*256 (coalesced stores), stepping y *= w with
// w = exp(dtA*256). Ceff (x2 for the final factor) is folded into y's
// initial value, so inner loop is: acc += y.re; y *= w.

constexpr int NM = 32;          // N/2 modes
constexpr int BLK = 256;        // threads per block (l-stride)

template<int SPLIT>
__global__ __launch_bounds__(BLK)
void s4d_vand_kernel(const float* __restrict__ Cv,
                     const float* __restrict__ log_dt,
                     const float* __restrict__ log_A_real,
                     const float* __restrict__ A_imag,
                     float* __restrict__ K, int L)
{
    const int h    = blockIdx.x / SPLIT;
    const int seg  = blockIdx.x % SPLIT;
    const int Lseg = L / SPLIT;
    const int l0   = seg * Lseg;
    const int t    = threadIdx.x;

    __shared__ float sm_dr[NM], sm_di[NM], sm_cr[NM], sm_ci[NM],
                     sm_wr[NM], sm_wi[NM];

    if (t < NM) {
        const int n = t;
        const float dt = __expf(log_dt[h]);
        const float ar = -__expf(log_A_real[h * NM + n]);
        const float ai = A_imag[h * NM + n];
        const float dr = ar * dt;          // Re(dtA)  (negative)
        const float di = ai * dt;          // Im(dtA)
        // E = exp(dtA) - 1
        const float em = __expf(dr);
        float es, ec;
        __sincosf(di, &es, &ec);
        const float Er = em * ec - 1.0f;
        const float Ei = em * es;
        const float cr = Cv[(h * NM + n) * 2 + 0];
        const float ci = Cv[(h * NM + n) * 2 + 1];
        // num = C * E
        const float nr = cr * Er - ci * Ei;
        const float ni = cr * Ei + ci * Er;
        // Ceff2 = 2 * num * conj(A) / |A|^2
        const float inv = 2.0f / (ar * ar + ai * ai);
        sm_dr[n] = dr;
        sm_di[n] = di;
        sm_cr[n] = (nr * ar + ni * ai) * inv;
        sm_ci[n] = (ni * ar - nr * ai) * inv;
        // recurrence multiplier across the thread stride: w = exp(dtA*BLK)
        const float wm = __expf(dr * (float)BLK);
        float ws, wc;
        __sincosf(di * (float)BLK, &ws, &wc);
        sm_wr[n] = wm * wc;
        sm_wi[n] = wm * ws;
    }
    __syncthreads();

    // Per-thread state: y[n] = Ceff2 * exp(dtA*(l0+t)), w[n] in registers.
    float yr[NM], yi[NM], wr[NM], wi[NM];
    const float ll = (float)(l0 + t);
    #pragma unroll
    for (int n = 0; n < NM; ++n) {
        const float dr  = sm_dr[n], di  = sm_di[n];
        const float c2r = sm_cr[n], c2i = sm_ci[n];
        wr[n] = sm_wr[n];
        wi[n] = sm_wi[n];
        const float zm = __expf(dr * ll);
        float zs, zc;
        __sincosf(di * ll, &zs, &zc);
        const float zr = zm * zc, zi = zm * zs;
        yr[n] = c2r * zr - c2i * zi;
        yi[n] = c2r * zi + c2i * zr;
    }

    float* __restrict__ out = K + (size_t)h * L + l0 + t;
    const int nsteps = Lseg >> 8;      // Lseg / BLK
    for (int s = 0; s < nsteps; ++s) {
        float a0 = 0.f, a1 = 0.f, a2 = 0.f, a3 = 0.f;
        #pragma unroll
        for (int n = 0; n < NM; n += 4) {
            a0 += yr[n + 0];
            a1 += yr[n + 1];
            a2 += yr[n + 2];
            a3 += yr[n + 3];
            #pragma unroll
            for (int k = 0; k < 4; ++k) {
                const float oyr = yr[n + k], oyi = yi[n + k];
                const float owr = wr[n + k], owi = wi[n + k];
                yr[n + k] = oyr * owr - oyi * owi;
                yi[n + k] = oyr * owi + oyi * owr;
            }
        }
        out[s * BLK] = (a0 + a1) + (a2 + a3);
    }
}

extern "C" void kernel_launch(void* const* d_in, const int* in_sizes, int n_in,
                              void* d_out, int out_size, void* d_ws, size_t ws_size,
                              hipStream_t stream) {
    const float* Cv         = (const float*)d_in[0];   // (H, 32, 2)
    const float* log_dt     = (const float*)d_in[1];   // (H,)
    const float* log_A_real = (const float*)d_in[2];   // (H, 32)
    const float* A_imag     = (const float*)d_in[3];   // (H, 32)
    float* K = (float*)d_out;                          // (H, L) fp32

    const int H = in_sizes[1];
    const int L = out_size / H;                        // 4096

    constexpr int SPLIT = 2;                           // L-segments per h
    dim3 grid(H * SPLIT), block(BLK);
    hipLaunchKernelGGL(s4d_vand_kernel<SPLIT>, grid, block, 0, stream,
                       Cv, log_dt, log_A_real, A_imag, K, L);
}

// Round 2
// 18.342 us; speedup vs baseline: 1.7229x; 1.7229x over previous
//
#include <hip/hip_runtime.h>

// S4D Vandermonde: K[h,l] = 2*Re( sum_n Ceff[h,n] * z_n^l ),  z_n = exp(dtA[h,n])
//
// R1 -> R2: replace the complex-multiply recurrence (5 instr/term) with a
// REAL two-term recurrence packed over mode pairs (v_pk_fma_f32):
//   x_s = Re(Ceff2 * z^(t) * Z^s),  Z = z^256
//   x_{s+1} = 2*Re(Z) * x_s - |Z|^2 * x_{s-1}
// -> 3 packed instr per 2 terms = 1.5 instr/term.
// SPLIT=1: 16 steps/thread amortizes the per-thread trig init 2x better.

typedef float f32x2 __attribute__((ext_vector_type(2)));
typedef float f32x4 __attribute__((ext_vector_type(4)));

constexpr int NM  = 32;   // modes (N/2)
constexpr int NP  = 16;   // mode pairs
constexpr int BLK = 256;  // threads per block; thread t owns l = t + BLK*s

__global__ __launch_bounds__(BLK)
void s4d_rec_kernel(const float* __restrict__ Cv,
                    const float* __restrict__ log_dt,
                    const float* __restrict__ log_A_real,
                    const float* __restrict__ A_imag,
                    float* __restrict__ K, int L)
{
    const int h = blockIdx.x;
    const int t = threadIdx.x;

    __shared__ f32x4 sm0[NM];   // {sig, om, c2r, c2i}  (dtA = sig + i*om, Ceff2)
    __shared__ f32x2 smz[NM];   // Z = z^BLK = {Zr, Zi}

    if (t < NM) {
        const int n = t;
        const float dt = __expf(log_dt[h]);
        const float ar = -__expf(log_A_real[h * NM + n]);
        const float ai = A_imag[h * NM + n];
        const float sig = ar * dt;            // Re(dtA) <= 0
        const float om  = ai * dt;            // Im(dtA)
        // E = exp(dtA) - 1
        const float em = __expf(sig);
        float es, ec;
        __sincosf(om, &es, &ec);
        const float Er = em * ec - 1.0f;
        const float Ei = em * es;
        const float cr = Cv[(h * NM + n) * 2 + 0];
        const float ci = Cv[(h * NM + n) * 2 + 1];
        // num = C * E;  Ceff2 = 2 * num * conj(A) / |A|^2
        const float nr = cr * Er - ci * Ei;
        const float ni = cr * Ei + ci * Er;
        const float inv = 2.0f / (ar * ar + ai * ai);
        f32x4 v0;
        v0.x = sig;
        v0.y = om;
        v0.z = (nr * ar + ni * ai) * inv;
        v0.w = (ni * ar - nr * ai) * inv;
        sm0[n] = v0;
        // Z = z^BLK
        const float mb = __expf(sig * (float)BLK);
        float bs, bc;
        __sincosf(om * (float)BLK, &bs, &bc);
        f32x2 z;
        z.x = mb * bc;
        z.y = mb * bs;
        smz[n] = z;
    }
    __syncthreads();

    // Per-thread state, mode pairs packed into f32x2 -> v_pk_* fp32 ops.
    f32x2 X0[NP], X1[NP], Ac[NP], Bc[NP];
    const float tf = (float)t;
    #pragma unroll
    for (int n = 0; n < NM; ++n) {
        const f32x4 c0 = sm0[n];
        const f32x2 z  = smz[n];
        const float m = __expf(c0.x * tf);
        float zs, zc;
        __sincosf(c0.y * tf, &zs, &zc);
        const float zr = m * zc, zi = m * zs;
        // y0 = Ceff2 * z^t
        const float y0r = c0.z * zr - c0.w * zi;
        const float y0i = c0.z * zi + c0.w * zr;
        X0[n >> 1][n & 1] = y0r;                       // x at s=0
        X1[n >> 1][n & 1] = y0r * z.x - y0i * z.y;     // x at s=1 (Re(y0*Z))
        Ac[n >> 1][n & 1] = 2.0f * z.x;                // 2*Re(Z)
        Bc[n >> 1][n & 1] = z.x * z.x + z.y * z.y;     // |Z|^2
    }

    float* __restrict__ out = K + (size_t)h * L + t;
    const int nsteps = L >> 8;   // L / BLK = 16

    f32x2 acc0 = {0.f, 0.f}, acc1 = {0.f, 0.f};
    #pragma unroll
    for (int p = 0; p < NP; ++p) { acc0 += X0[p]; acc1 += X1[p]; }
    out[0]   = acc0.x + acc0.y;
    out[BLK] = acc1.x + acc1.y;

    for (int s = 2; s < nsteps; s += 2) {
        f32x2 acc = {0.f, 0.f};
        #pragma unroll
        for (int p = 0; p < NP; ++p) {
            X0[p] = Ac[p] * X1[p] - Bc[p] * X0[p];     // x_s
            acc += X0[p];
        }
        out[(size_t)s * BLK] = acc.x + acc.y;
        f32x2 accb = {0.f, 0.f};
        #pragma unroll
        for (int p = 0; p < NP; ++p) {
            X1[p] = Ac[p] * X0[p] - Bc[p] * X1[p];     // x_{s+1}
            accb += X1[p];
        }
        out[(size_t)(s + 1) * BLK] = accb.x + accb.y;
    }
}

extern "C" void kernel_launch(void* const* d_in, const int* in_sizes, int n_in,
                              void* d_out, int out_size, void* d_ws, size_t ws_size,
                              hipStream_t stream) {
    const float* Cv         = (const float*)d_in[0];   // (H, 32, 2)
    const float* log_dt     = (const float*)d_in[1];   // (H,)
    const float* log_A_real = (const float*)d_in[2];   // (H, 32)
    const float* A_imag     = (const float*)d_in[3];   // (H, 32)
    float* K = (float*)d_out;                          // (H, L) fp32

    const int H = in_sizes[1];
    const int L = out_size / H;                        // 4096

    dim3 grid(H), block(BLK);
    hipLaunchKernelGGL(s4d_rec_kernel, grid, block, 0, stream,
                       Cv, log_dt, log_A_real, A_imag, K, L);
}